// Round 3
// baseline (1182.426 us; speedup 1.0000x reference)
//
#include <hip/hip_runtime.h>
#include <cmath>

#define D 64
#define BLK 256
#define KC 128         // k-chunk staged in LDS
#define MARGIN 1e-2f   // fp32 top-2 gap below this -> fp64 refine (fp32 err bound ~2.5e-4)
#define NPMAX 8        // max partitioned copies of scatter accumulators

// ---------------- K0: wn[k] = 0.5*||w_k||^2 (fp32) ----------------
__global__ void k_wn(const float* __restrict__ w, float* __restrict__ wn, int K) {
    int k = blockIdx.x * blockDim.x + threadIdx.x;
    if (k >= K) return;
    float s = 0.f;
    for (int d = 0; d < D; ++d) {
        float v = w[(size_t)d * K + k];
        s = fmaf(v, v, s);
    }
    wn[k] = 0.5f * s;
}

// ---------------- K2: fp32 argmax of t_k = x.w_k - wn_k, top-2 margin flag ----------------
// waves_per_eu(4,4) pins the VGPR budget at 128: xa(64) + operands + argmax
// state ~= 95 regs -> provably no scratch spill (R2's VGPR=60 + 125MB spill
// traffic came from the compiler chasing 8 waves/EU).
__global__ __launch_bounds__(BLK)
__attribute__((amdgpu_waves_per_eu(4, 4)))
void k_assign(
    const float* __restrict__ x, const float* __restrict__ w,
    const float* __restrict__ wn, unsigned int* __restrict__ idx_out,
    float* __restrict__ quant, int N, int K)
{
    __shared__ float lds_w[KC][D + 4];   // 128*68*4 = 34816 B -> 4 blocks/CU
    __shared__ float lds_wn[KC];
    const int tid = threadIdx.x;
    const long long n = (long long)blockIdx.x * BLK + tid;
    const long long nn = (n < N) ? n : (N - 1);

    // x row -> registers (16 float4 = 64 VGPRs)
    float4 xa[D / 4];
    {
        const float4* xr = (const float4*)(x + nn * D);
        #pragma unroll
        for (int i = 0; i < D / 4; ++i) xa[i] = xr[i];
    }

    float best = -INFINITY, sec = -INFINITY;
    int bi = 0;

    const int kown  = tid & (KC - 1);     // code this thread stages
    const int dhalf = tid >> 7;           // 0 or 1: which 32-dim half

    for (int k0 = 0; k0 < K; k0 += KC) {
        __syncthreads();
        // stage chunk: 256 threads cover 128 codes x 2 dim-halves
        #pragma unroll 8
        for (int i = 0; i < 32; ++i) {
            int d = dhalf * 32 + i;
            lds_w[kown][d] = w[(size_t)d * K + (k0 + kown)];
        }
        if (dhalf == 0) lds_wn[kown] = wn[k0 + kown];
        __syncthreads();

        for (int kc = 0; kc < KC; ++kc) {
            const float4* wr = (const float4*)(&lds_w[kc][0]);  // broadcast reads
            float da = -lds_wn[kc], db = 0.f;   // 2 independent chains
            #pragma unroll
            for (int i = 0; i < D / 8; ++i) {
                float4 wv0 = wr[2 * i], wv1 = wr[2 * i + 1];
                float4 xv0 = xa[2 * i], xv1 = xa[2 * i + 1];
                da = fmaf(xv0.x, wv0.x, da);
                db = fmaf(xv1.x, wv1.x, db);
                da = fmaf(xv0.y, wv0.y, da);
                db = fmaf(xv1.y, wv1.y, db);
                da = fmaf(xv0.z, wv0.z, da);
                db = fmaf(xv1.z, wv1.z, db);
                da = fmaf(xv0.w, wv0.w, da);
                db = fmaf(xv1.w, wv1.w, db);
            }
            float dot = da + db;
            // strict > keeps smallest k on exact ties (argmax first-occurrence)
            bool g = dot > best;
            sec  = g ? best : fmaxf(sec, dot);
            best = g ? dot : best;
            bi   = g ? (k0 + kc) : bi;
        }
    }

    if (n < N) {
        unsigned flag = ((best - sec) < MARGIN) ? 0x80000000u : 0u;
        idx_out[n] = (unsigned)bi | flag;
        const float* wc = w + bi;
        float4* qd = (float4*)(quant + n * D);
        #pragma unroll
        for (int i = 0; i < D / 4; ++i) {
            float4 q;
            q.x = wc[(size_t)(4 * i + 0) * K];
            q.y = wc[(size_t)(4 * i + 1) * K];
            q.z = wc[(size_t)(4 * i + 2) * K];
            q.w = wc[(size_t)(4 * i + 3) * K];
            qd[i] = q;
        }
    }
}

// ---------------- K3: fp64 exact rescan of flagged points (rare) ----------------
__global__ void k_refine(const float* __restrict__ x, const float* __restrict__ w,
                         unsigned int* __restrict__ idx_io, float* __restrict__ quant,
                         int N, int K)
{
    const int gtid = blockIdx.x * blockDim.x + threadIdx.x;
    const int lane = threadIdx.x & 63;
    const long long wave = gtid >> 6;
    const long long nwaves = (long long)(gridDim.x * blockDim.x) >> 6;

    for (long long base = wave * 64; base < N; base += nwaves * 64) {
        long long nl = base + lane;
        unsigned v = (nl < (long long)N) ? idx_io[nl] : 0u;
        unsigned long long flags = __ballot(v >> 31);
        while (flags) {
            int j = __ffsll(flags) - 1;
            flags &= flags - 1;
            long long p = base + j;
            float xr[D];
            #pragma unroll 8
            for (int d = 0; d < D; ++d) xr[d] = x[p * D + d];
            double bt = -1e300;
            int bk = 0;
            for (int k = lane; k < K; k += 64) {   // ascending k per lane; strict > = first-occurrence
                double t = 0.0, s = 0.0;
                #pragma unroll 8
                for (int d = 0; d < D; ++d) {
                    double wd = (double)w[(size_t)d * K + k];
                    t = fma((double)xr[d], wd, t);
                    s = fma(wd, wd, s);
                }
                t -= 0.5 * s;
                if (t > bt) { bt = t; bk = k; }
            }
            #pragma unroll
            for (int off = 32; off > 0; off >>= 1) {
                double ot = __shfl_down(bt, off);
                int    ok = __shfl_down(bk, off);
                if (ot > bt || (ot == bt && ok < bk)) { bt = ot; bk = ok; }
            }
            int fk = __shfl(bk, 0);
            if (lane == 0) idx_io[p] = (unsigned)fk;     // clear flag
            quant[p * D + lane] = w[(size_t)lane * K + fk];
        }
    }
}

// ---------------- K4: scatter x into NP private [K][D] partial sums + counts ----------------
__global__ void k_scatter(const float* __restrict__ x, const unsigned int* __restrict__ idx,
                          float* __restrict__ cs, float* __restrict__ cn, int N, int K, int NP)
{
    const int gtid = blockIdx.x * blockDim.x + threadIdx.x;
    const int lane = threadIdx.x & 63;
    const long long wave = gtid >> 6;
    const long long nwaves = (long long)(gridDim.x * blockDim.x) >> 6;
    const int part = blockIdx.x % NP;
    float* csp = cs + (size_t)part * K * D;
    float* cnp = cn + (size_t)part * K;
    for (long long p = wave; p < N; p += nwaves) {
        unsigned k = idx[p] & 0x7fffffffu;
        float v = x[p * D + lane];
        unsafeAtomicAdd(&csp[(size_t)k * D + lane], v);   // coalesced 256B burst per wave
        if (lane == 0) unsafeAtomicAdd(&cnp[k], 1.0f);
    }
}

// ---------------- K5: reduce NP partials + EMA combine -> new_w [D][K] ----------------
__global__ void k_combine(const float* __restrict__ c_sum, const float* __restrict__ c_n,
                          const float* __restrict__ cs, const float* __restrict__ cn,
                          float* __restrict__ outw, int K, int NP)
{
    int i = blockIdx.x * blockDim.x + threadIdx.x;   // i = d*K + k
    if (i >= D * K) return;
    int k = i % K;
    int d = i / K;
    float s = 0.f, nk = 0.f;
    for (int p = 0; p < NP; ++p) {
        s  += cs[(size_t)p * K * D + (size_t)k * D + d];
        nk += cn[(size_t)p * K + k];
    }
    const float g  = 0.99f;
    const float og = (float)(1.0 - 0.99);
    float ns = c_sum[i] * g + s * og;
    float nn = c_n[k] * g + nk * og;
    outw[i] = ns / nn;
}

extern "C" void kernel_launch(void* const* d_in, const int* in_sizes, int n_in,
                              void* d_out, int out_size, void* d_ws, size_t ws_size,
                              hipStream_t stream)
{
    const float* x     = (const float*)d_in[0];
    const float* w     = (const float*)d_in[1];
    const float* c_sum = (const float*)d_in[2];
    const float* c_n   = (const float*)d_in[3];
    const int N = in_sizes[0] / D;
    const int K = in_sizes[3];

    float* quant = (float*)d_out;                      // N*D
    float* outw  = (float*)d_out + (size_t)N * D;      // D*K

    // pick NP partitions that fit the workspace
    size_t fixed = (size_t)N * 4 + (size_t)K * 4;      // idx + wn
    int NP = NPMAX;
    while (NP > 1 && fixed + (size_t)NP * K * (D + 1) * 4 > ws_size) NP >>= 1;

    char* ws = (char*)d_ws;
    unsigned* idx = (unsigned*)ws;                                     // N ints
    float* cs = (float*)(ws + (size_t)N * 4);                          // NP*K*D
    float* cn = cs + (size_t)NP * K * D;                               // NP*K
    float* wn = cn + (size_t)NP * K;                                   // K

    hipMemsetAsync(cs, 0, (size_t)NP * K * (D + 1) * sizeof(float), stream);
    k_wn<<<(K + 255) / 256, 256, 0, stream>>>(w, wn, K);

    int grid_assign = (N + BLK - 1) / BLK;                             // 1024 blocks
    k_assign<<<grid_assign, BLK, 0, stream>>>(x, w, wn, idx, quant, N, K);

    k_refine<<<256, 256, 0, stream>>>(x, w, idx, quant, N, K);
    k_scatter<<<512, 256, 0, stream>>>(x, idx, cs, cn, N, K, NP);
    k_combine<<<(D * K + 255) / 256, 256, 0, stream>>>(c_sum, c_n, cs, cn, outw, K, NP);
}

// Round 4
// 527.045 us; speedup vs baseline: 2.2435x; 2.2435x over previous
//
#include <hip/hip_runtime.h>
#include <cmath>

#define D 64
#define MARGIN 1e-2f   // approx top-2 gap below this -> fp64 refine (bf16-split err <= ~2.5e-3)
#define NPMAX 8        // max partitioned copies of scatter accumulators

typedef __attribute__((ext_vector_type(8))) short short8;   // 8 bf16 = 4 VGPRs (MFMA A/B frag)
typedef __attribute__((ext_vector_type(4))) float f32x4;    // MFMA C/D frag

// round-to-nearest-even fp32 -> bf16 (bits), and the payload remainder
__device__ __forceinline__ unsigned short bf16_rne(float f) {
    unsigned u = __float_as_uint(f);
    return (unsigned short)((u + 0x7FFFu + ((u >> 16) & 1u)) >> 16);
}
__device__ __forceinline__ float bf16_hi_as_f32(float f, unsigned short* hbits) {
    unsigned u = __float_as_uint(f);
    unsigned uh = (u + 0x7FFFu + ((u >> 16) & 1u)) & 0xFFFF0000u;
    *hbits = (unsigned short)(uh >> 16);
    return __uint_as_float(uh);
}

// ---------------- K0: pack w into MFMA B-frag layout (hi/lo bf16) + transpose ----------------
// wpack[((t*2+kc)*64 + quad*16 + n)*8 + j] = w[d = kc*32+quad*8+j][code = t*16+n]
__global__ void k_prep_w(const float* __restrict__ w, unsigned short* __restrict__ wpack_hi,
                         unsigned short* __restrict__ wpack_lo, float* __restrict__ wT, int K)
{
    int i = blockIdx.x * blockDim.x + threadIdx.x;   // i = d*K + k, coalesced over k
    if (i >= D * K) return;
    int d = i / K, k = i % K;
    float f = w[i];
    unsigned short hb;
    float fh = bf16_hi_as_f32(f, &hb);
    unsigned short lb = bf16_rne(f - fh);
    int t = k >> 4, n = k & 15;
    int kc = d >> 5, q = (d >> 3) & 3, j = d & 7;
    size_t fi = ((size_t)((t * 2 + kc) * 64 + q * 16 + n)) * 8 + j;
    wpack_hi[fi] = hb;
    wpack_lo[fi] = lb;
    wT[(size_t)k * D + d] = f;
}

// ---------------- K1: wn[k] = 0.5*||w_k||^2 (fp64 accum) ----------------
__global__ void k_wn(const float* __restrict__ w, float* __restrict__ wn, int K) {
    int k = blockIdx.x * blockDim.x + threadIdx.x;
    if (k >= K) return;
    double s = 0.0;
    for (int d = 0; d < D; ++d) {
        double v = (double)w[(size_t)d * K + k];
        s += v * v;
    }
    wn[k] = (float)(0.5 * s);
}

// ---------------- K2: MFMA assign: argmax_k (x.w_k - wn_k), top-2 margin flag ----------------
// wave = 32 points (2 m-tiles); block = 4 waves = 128 points; K staged in LDS 128 codes/chunk
__global__ __launch_bounds__(256, 4) void k_assign(
    const float* __restrict__ x, const unsigned short* __restrict__ wpack_hi,
    const unsigned short* __restrict__ wpack_lo, const float* __restrict__ wn,
    unsigned int* __restrict__ idx_out, int N, int K)
{
    __shared__ __align__(16) unsigned short lds_hi[8192];  // 16 KB: 8 tiles x 2 kc x 1KB
    __shared__ __align__(16) unsigned short lds_lo[8192];  // 16 KB
    __shared__ float lds_wn[128];

    const int tid = threadIdx.x;
    const int wv = tid >> 6, lane = tid & 63;
    const int col = lane & 15, quad = lane >> 4;
    const long long n0 = (long long)blockIdx.x * 128 + wv * 32;

    // Build A-frags in registers: lane holds A[m=col][k=quad*8+j], hi/lo split.
    short8 a_hi[2][2], a_lo[2][2];
    #pragma unroll
    for (int mt = 0; mt < 2; ++mt) {
        long long row = n0 + mt * 16 + col;
        if (row >= N) row = N - 1;
        const float* xr = x + row * D;
        #pragma unroll
        for (int kc = 0; kc < 2; ++kc) {
            const int dbase = kc * 32 + quad * 8;
            float4 f0 = *(const float4*)(xr + dbase);
            float4 f1 = *(const float4*)(xr + dbase + 4);
            float xs[8] = {f0.x, f0.y, f0.z, f0.w, f1.x, f1.y, f1.z, f1.w};
            short8 h, l;
            #pragma unroll
            for (int j = 0; j < 8; ++j) {
                unsigned short hb;
                float fh = bf16_hi_as_f32(xs[j], &hb);
                h[j] = (short)hb;
                l[j] = (short)bf16_rne(xs[j] - fh);
            }
            a_hi[mt][kc] = h;
            a_lo[mt][kc] = l;
        }
    }

    float best[8], sec[8];
    int bidx[8];
    #pragma unroll
    for (int s = 0; s < 8; ++s) { best[s] = -INFINITY; sec[s] = -INFINITY; bidx[s] = 0; }

    const int nchunks = K / 128;
    for (int c = 0; c < nchunks; ++c) {
        __syncthreads();
        {   // stage 32 KB (hi+lo) + 512 B wn: straight contiguous copy
            const uint4* gh = (const uint4*)(wpack_hi + (size_t)c * 8192);
            const uint4* gl = (const uint4*)(wpack_lo + (size_t)c * 8192);
            uint4* lh = (uint4*)lds_hi;
            uint4* ll = (uint4*)lds_lo;
            #pragma unroll
            for (int i = 0; i < 4; ++i) {   // 1024 uint4 per array / 256 threads
                lh[tid + 256 * i] = gh[tid + 256 * i];
                ll[tid + 256 * i] = gl[tid + 256 * i];
            }
            if (tid < 128) lds_wn[tid] = wn[c * 128 + tid];
        }
        __syncthreads();

        #pragma unroll
        for (int tl = 0; tl < 8; ++tl) {
            const int fb = (tl * 2) * 512 + (quad * 16 + col) * 8;   // element index
            short8 bh0 = *(const short8*)(lds_hi + fb);
            short8 bl0 = *(const short8*)(lds_lo + fb);
            short8 bh1 = *(const short8*)(lds_hi + fb + 512);
            short8 bl1 = *(const short8*)(lds_lo + fb + 512);
            const float wnv = lds_wn[tl * 16 + col];
            const int code = (c * 8 + tl) * 16 + col;
            #pragma unroll
            for (int mt = 0; mt < 2; ++mt) {
                f32x4 acc = {0.f, 0.f, 0.f, 0.f};
                acc = __builtin_amdgcn_mfma_f32_16x16x32_bf16(a_hi[mt][0], bh0, acc, 0, 0, 0);
                acc = __builtin_amdgcn_mfma_f32_16x16x32_bf16(a_hi[mt][1], bh1, acc, 0, 0, 0);
                acc = __builtin_amdgcn_mfma_f32_16x16x32_bf16(a_lo[mt][0], bh0, acc, 0, 0, 0);
                acc = __builtin_amdgcn_mfma_f32_16x16x32_bf16(a_lo[mt][1], bh1, acc, 0, 0, 0);
                acc = __builtin_amdgcn_mfma_f32_16x16x32_bf16(a_hi[mt][0], bl0, acc, 0, 0, 0);
                acc = __builtin_amdgcn_mfma_f32_16x16x32_bf16(a_hi[mt][1], bl1, acc, 0, 0, 0);
                #pragma unroll
                for (int r = 0; r < 4; ++r) {
                    float v = acc[r] - wnv;
                    int s = mt * 4 + r;
                    bool g = v > best[s];             // strict >: smallest code wins ties
                    sec[s]  = g ? best[s] : fmaxf(sec[s], v);
                    best[s] = g ? v : best[s];
                    bidx[s] = g ? code : bidx[s];
                }
            }
        }
    }

    // top-2 merge across the 16 columns (lanes sharing a quad-group)
    #pragma unroll
    for (int m = 1; m < 16; m <<= 1) {
        #pragma unroll
        for (int s = 0; s < 8; ++s) {
            float ob = __shfl_xor(best[s], m);
            float os = __shfl_xor(sec[s], m);
            int   oi = __shfl_xor(bidx[s], m);
            bool take = (ob > best[s]) || (ob == best[s] && oi < bidx[s]);
            float nsec = take ? fmaxf(os, best[s]) : fmaxf(sec[s], ob);
            best[s] = take ? ob : best[s];
            bidx[s] = take ? oi : bidx[s];
            sec[s]  = nsec;
        }
    }

    if (col == 0) {
        #pragma unroll
        for (int s = 0; s < 8; ++s) {
            int mt = s >> 2, r = s & 3;
            long long np = n0 + mt * 16 + quad * 4 + r;   // C row = quad*4 + reg
            if (np < N) {
                unsigned fl = ((best[s] - sec[s]) < MARGIN) ? 0x80000000u : 0u;
                idx_out[np] = (unsigned)bidx[s] | fl;
            }
        }
    }
}

// ---------------- K3: fp64 exact rescan of flagged points (rare) ----------------
__global__ void k_refine(const float* __restrict__ x, const float* __restrict__ w,
                         unsigned int* __restrict__ idx_io, int N, int K)
{
    const int gtid = blockIdx.x * blockDim.x + threadIdx.x;
    const int lane = threadIdx.x & 63;
    const long long wave = gtid >> 6;
    const long long nwaves = (long long)(gridDim.x * blockDim.x) >> 6;

    for (long long base = wave * 64; base < N; base += nwaves * 64) {
        long long nl = base + lane;
        unsigned v = (nl < (long long)N) ? idx_io[nl] : 0u;
        unsigned long long flags = __ballot(v >> 31);
        while (flags) {
            int j = __ffsll(flags) - 1;
            flags &= flags - 1;
            long long p = base + j;
            float xr[D];
            #pragma unroll 8
            for (int d = 0; d < D; ++d) xr[d] = x[p * D + d];
            double bt = -1e300;
            int bk = 0;
            for (int k = lane; k < K; k += 64) {   // ascending k per lane; strict > = first-occurrence
                double t = 0.0, s = 0.0;
                #pragma unroll 8
                for (int d = 0; d < D; ++d) {
                    double wd = (double)w[(size_t)d * K + k];
                    t = fma((double)xr[d], wd, t);
                    s = fma(wd, wd, s);
                }
                t -= 0.5 * s;
                if (t > bt) { bt = t; bk = k; }
            }
            #pragma unroll
            for (int off = 32; off > 0; off >>= 1) {
                double ot = __shfl_down(bt, off);
                int    ok = __shfl_down(bk, off);
                if (ot > bt || (ot == bt && ok < bk)) { bt = ot; bk = ok; }
            }
            int fk = __shfl(bk, 0);
            if (lane == 0) idx_io[p] = (unsigned)fk;     // clear flag
        }
    }
}

// ---------------- K4: fused quantized-gather + EMA scatter (wave per point) ----------------
__global__ void k_scatgat(const float* __restrict__ x, const float* __restrict__ wT,
                          const unsigned int* __restrict__ idx, float* __restrict__ quant,
                          float* __restrict__ cs, float* __restrict__ cn, int N, int K, int NP)
{
    const int gtid = blockIdx.x * blockDim.x + threadIdx.x;
    const int lane = threadIdx.x & 63;
    const long long wave = gtid >> 6;
    const long long nwaves = (long long)(gridDim.x * blockDim.x) >> 6;
    const int part = blockIdx.x % NP;
    float* csp = cs + (size_t)part * K * D;
    float* cnp = cn + (size_t)part * K;
    for (long long p = wave; p < N; p += nwaves) {
        unsigned k = idx[p] & 0x7fffffffu;
        float v = x[p * D + lane];
        quant[p * D + lane] = wT[(size_t)k * D + lane];       // coalesced 256B gather (L2-hot)
        unsafeAtomicAdd(&csp[(size_t)k * D + lane], v);       // coalesced 256B atomic burst
        if (lane == 0) unsafeAtomicAdd(&cnp[k], 1.0f);
    }
}

// ---------------- K5: reduce NP partials + EMA combine -> new_w [D][K] ----------------
__global__ void k_combine(const float* __restrict__ c_sum, const float* __restrict__ c_n,
                          const float* __restrict__ cs, const float* __restrict__ cn,
                          float* __restrict__ outw, int K, int NP)
{
    int i = blockIdx.x * blockDim.x + threadIdx.x;   // i = d*K + k
    if (i >= D * K) return;
    int k = i % K;
    int d = i / K;
    float s = 0.f, nk = 0.f;
    for (int p = 0; p < NP; ++p) {
        s  += cs[(size_t)p * K * D + (size_t)k * D + d];
        nk += cn[(size_t)p * K + k];
    }
    const float g  = 0.99f;
    const float og = (float)(1.0 - 0.99);
    float ns = c_sum[i] * g + s * og;
    float nn = c_n[k] * g + nk * og;
    outw[i] = ns / nn;
}

extern "C" void kernel_launch(void* const* d_in, const int* in_sizes, int n_in,
                              void* d_out, int out_size, void* d_ws, size_t ws_size,
                              hipStream_t stream)
{
    const float* x     = (const float*)d_in[0];
    const float* w     = (const float*)d_in[1];
    const float* c_sum = (const float*)d_in[2];
    const float* c_n   = (const float*)d_in[3];
    const int N = in_sizes[0] / D;
    const int K = in_sizes[3];

    float* quant = (float*)d_out;                      // N*D
    float* outw  = (float*)d_out + (size_t)N * D;      // D*K

    // workspace layout (all 16B-aligned): cs | cn | wn | wT | idx | wpack_hi | wpack_lo
    size_t fixed = (size_t)K * 4 + (size_t)K * D * 4 + (size_t)N * 4 + (size_t)K * D * 2 * 2;
    int NP = NPMAX;
    while (NP > 1 && fixed + (size_t)NP * K * (D + 1) * 4 > ws_size) NP >>= 1;

    char* ws = (char*)d_ws;
    float* cs = (float*)ws;                                            // NP*K*D
    float* cn = cs + (size_t)NP * K * D;                               // NP*K
    float* wn = cn + (size_t)NP * K;                                   // K
    float* wT = wn + K;                                                // K*D
    unsigned* idx = (unsigned*)(wT + (size_t)K * D);                   // N
    unsigned short* wpack_hi = (unsigned short*)(idx + N);             // K*D
    unsigned short* wpack_lo = wpack_hi + (size_t)K * D;               // K*D

    hipMemsetAsync(cs, 0, (size_t)NP * K * (D + 1) * sizeof(float), stream);
    k_prep_w<<<(D * K + 255) / 256, 256, 0, stream>>>(w, wpack_hi, wpack_lo, wT, K);
    k_wn<<<(K + 255) / 256, 256, 0, stream>>>(w, wn, K);

    int grid_assign = (N + 127) / 128;                                 // 2048 blocks
    k_assign<<<grid_assign, 256, 0, stream>>>(x, wpack_hi, wpack_lo, wn, idx, N, K);

    k_refine<<<256, 256, 0, stream>>>(x, w, idx, N, K);
    k_scatgat<<<1024, 256, 0, stream>>>(x, wT, idx, quant, cs, cn, N, K, NP);
    k_combine<<<(D * K + 255) / 256, 256, 0, stream>>>(c_sum, c_n, cs, cn, outw, K, NP);
}

// Round 5
// 453.729 us; speedup vs baseline: 2.6060x; 1.1616x over previous
//
#include <hip/hip_runtime.h>
#include <cmath>

#define D 64
#define MARGIN 1e-2f   // approx top-2 gap below this -> fp64 refine (bf16-split err <= ~2.5e-3)
#define NPMAX 8        // max partitioned copies of scatter accumulators

typedef __attribute__((ext_vector_type(8))) short short8;   // 8 bf16 = 4 VGPRs (MFMA A/B frag)
typedef __attribute__((ext_vector_type(4))) float f32x4;    // MFMA C/D frag

// round-to-nearest-even fp32 -> bf16 (bits), and the payload remainder
__device__ __forceinline__ unsigned short bf16_rne(float f) {
    unsigned u = __float_as_uint(f);
    return (unsigned short)((u + 0x7FFFu + ((u >> 16) & 1u)) >> 16);
}
__device__ __forceinline__ float bf16_hi_as_f32(float f, unsigned short* hbits) {
    unsigned u = __float_as_uint(f);
    unsigned uh = (u + 0x7FFFu + ((u >> 16) & 1u)) & 0xFFFF0000u;
    *hbits = (unsigned short)(uh >> 16);
    return __uint_as_float(uh);
}

// ---------------- K0: pack w into MFMA B-frag layout (hi/lo bf16) + transpose ----------------
// wpack[((t*2+kc)*64 + quad*16 + n)*8 + j] = w[d = kc*32+quad*8+j][code = t*16+n]
__global__ void k_prep_w(const float* __restrict__ w, unsigned short* __restrict__ wpack_hi,
                         unsigned short* __restrict__ wpack_lo, float* __restrict__ wT, int K)
{
    int i = blockIdx.x * blockDim.x + threadIdx.x;   // i = d*K + k, coalesced over k
    if (i >= D * K) return;
    int d = i / K, k = i % K;
    float f = w[i];
    unsigned short hb;
    float fh = bf16_hi_as_f32(f, &hb);
    unsigned short lb = bf16_rne(f - fh);
    int t = k >> 4, n = k & 15;
    int kc = d >> 5, q = (d >> 3) & 3, j = d & 7;
    size_t fi = ((size_t)((t * 2 + kc) * 64 + q * 16 + n)) * 8 + j;
    wpack_hi[fi] = hb;
    wpack_lo[fi] = lb;
    wT[(size_t)k * D + d] = f;
}

// ---------------- K1: wn[k] = 0.5*||w_k||^2 (fp64 accum) ----------------
__global__ void k_wn(const float* __restrict__ w, float* __restrict__ wn, int K) {
    int k = blockIdx.x * blockDim.x + threadIdx.x;
    if (k >= K) return;
    double s = 0.0;
    for (int d = 0; d < D; ++d) {
        double v = (double)w[(size_t)d * K + k];
        s += v * v;
    }
    wn[k] = (float)(0.5 * s);
}

// ---------------- K2: MFMA assign: argmax_k (x.w_k - wn_k), top-2 margin flag ----------------
// wave = 32 points (2 m-tiles); block = 4 waves = 128 points; K staged in LDS 128 codes/chunk
__global__ __launch_bounds__(256, 4) void k_assign(
    const float* __restrict__ x, const unsigned short* __restrict__ wpack_hi,
    const unsigned short* __restrict__ wpack_lo, const float* __restrict__ wn,
    unsigned int* __restrict__ idx_out, int N, int K)
{
    __shared__ __align__(16) unsigned short lds_hi[8192];  // 16 KB: 8 tiles x 2 kc x 1KB
    __shared__ __align__(16) unsigned short lds_lo[8192];  // 16 KB
    __shared__ float lds_wn[128];

    const int tid = threadIdx.x;
    const int wv = tid >> 6, lane = tid & 63;
    const int col = lane & 15, quad = lane >> 4;
    const long long n0 = (long long)blockIdx.x * 128 + wv * 32;

    // Build A-frags in registers: lane holds A[m=col][k=quad*8+j], hi/lo split.
    short8 a_hi[2][2], a_lo[2][2];
    #pragma unroll
    for (int mt = 0; mt < 2; ++mt) {
        long long row = n0 + mt * 16 + col;
        if (row >= N) row = N - 1;
        const float* xr = x + row * D;
        #pragma unroll
        for (int kc = 0; kc < 2; ++kc) {
            const int dbase = kc * 32 + quad * 8;
            float4 f0 = *(const float4*)(xr + dbase);
            float4 f1 = *(const float4*)(xr + dbase + 4);
            float xs[8] = {f0.x, f0.y, f0.z, f0.w, f1.x, f1.y, f1.z, f1.w};
            short8 h, l;
            #pragma unroll
            for (int j = 0; j < 8; ++j) {
                unsigned short hb;
                float fh = bf16_hi_as_f32(xs[j], &hb);
                h[j] = (short)hb;
                l[j] = (short)bf16_rne(xs[j] - fh);
            }
            a_hi[mt][kc] = h;
            a_lo[mt][kc] = l;
        }
    }

    float best[8], sec[8];
    int bidx[8];
    #pragma unroll
    for (int s = 0; s < 8; ++s) { best[s] = -INFINITY; sec[s] = -INFINITY; bidx[s] = 0; }

    const int nchunks = K / 128;
    for (int c = 0; c < nchunks; ++c) {
        __syncthreads();
        {   // stage 32 KB (hi+lo) + 512 B wn: straight contiguous copy
            const uint4* gh = (const uint4*)(wpack_hi + (size_t)c * 8192);
            const uint4* gl = (const uint4*)(wpack_lo + (size_t)c * 8192);
            uint4* lh = (uint4*)lds_hi;
            uint4* ll = (uint4*)lds_lo;
            #pragma unroll
            for (int i = 0; i < 4; ++i) {   // 1024 uint4 per array / 256 threads
                lh[tid + 256 * i] = gh[tid + 256 * i];
                ll[tid + 256 * i] = gl[tid + 256 * i];
            }
            if (tid < 128) lds_wn[tid] = wn[c * 128 + tid];
        }
        __syncthreads();

        #pragma unroll
        for (int tl = 0; tl < 8; ++tl) {
            const int fb = (tl * 2) * 512 + (quad * 16 + col) * 8;   // element index
            short8 bh0 = *(const short8*)(lds_hi + fb);
            short8 bl0 = *(const short8*)(lds_lo + fb);
            short8 bh1 = *(const short8*)(lds_hi + fb + 512);
            short8 bl1 = *(const short8*)(lds_lo + fb + 512);
            const float wnv = lds_wn[tl * 16 + col];
            const int code = (c * 8 + tl) * 16 + col;
            #pragma unroll
            for (int mt = 0; mt < 2; ++mt) {
                f32x4 acc = {0.f, 0.f, 0.f, 0.f};
                acc = __builtin_amdgcn_mfma_f32_16x16x32_bf16(a_hi[mt][0], bh0, acc, 0, 0, 0);
                acc = __builtin_amdgcn_mfma_f32_16x16x32_bf16(a_hi[mt][1], bh1, acc, 0, 0, 0);
                acc = __builtin_amdgcn_mfma_f32_16x16x32_bf16(a_lo[mt][0], bh0, acc, 0, 0, 0);
                acc = __builtin_amdgcn_mfma_f32_16x16x32_bf16(a_lo[mt][1], bh1, acc, 0, 0, 0);
                acc = __builtin_amdgcn_mfma_f32_16x16x32_bf16(a_hi[mt][0], bl0, acc, 0, 0, 0);
                acc = __builtin_amdgcn_mfma_f32_16x16x32_bf16(a_hi[mt][1], bl1, acc, 0, 0, 0);
                #pragma unroll
                for (int r = 0; r < 4; ++r) {
                    float v = acc[r] - wnv;
                    int s = mt * 4 + r;
                    bool g = v > best[s];             // strict >: smallest code wins ties
                    sec[s]  = g ? best[s] : fmaxf(sec[s], v);
                    best[s] = g ? v : best[s];
                    bidx[s] = g ? code : bidx[s];
                }
            }
        }
    }

    // top-2 merge across the 16 columns (lanes sharing a quad-group)
    #pragma unroll
    for (int m = 1; m < 16; m <<= 1) {
        #pragma unroll
        for (int s = 0; s < 8; ++s) {
            float ob = __shfl_xor(best[s], m);
            float os = __shfl_xor(sec[s], m);
            int   oi = __shfl_xor(bidx[s], m);
            bool take = (ob > best[s]) || (ob == best[s] && oi < bidx[s]);
            float nsec = take ? fmaxf(os, best[s]) : fmaxf(sec[s], ob);
            best[s] = take ? ob : best[s];
            bidx[s] = take ? oi : bidx[s];
            sec[s]  = nsec;
        }
    }

    if (col == 0) {
        #pragma unroll
        for (int s = 0; s < 8; ++s) {
            int mt = s >> 2, r = s & 3;
            long long np = n0 + mt * 16 + quad * 4 + r;   // C row = quad*4 + reg
            if (np < N) {
                unsigned fl = ((best[s] - sec[s]) < MARGIN) ? 0x80000000u : 0u;
                idx_out[np] = (unsigned)bidx[s] | fl;
            }
        }
    }
}

// ---------------- K3: fp64 exact rescan of flagged points (rare) ----------------
// NO per-thread x array (R4's VGPR=28 + scratch-thrash): x[p*D+d] is a wave-
// uniform broadcast load, L1-hot after the first k-iteration. w loads stay
// coalesced (lanes = consecutive k).
__global__ void k_refine(const float* __restrict__ x, const float* __restrict__ w,
                         unsigned int* __restrict__ idx_io, int N, int K)
{
    const int gtid = blockIdx.x * blockDim.x + threadIdx.x;
    const int lane = threadIdx.x & 63;
    const long long wave = gtid >> 6;
    const long long nwaves = (long long)(gridDim.x * blockDim.x) >> 6;

    for (long long base = wave * 64; base < N; base += nwaves * 64) {
        long long nl = base + lane;
        unsigned v = (nl < (long long)N) ? idx_io[nl] : 0u;
        unsigned long long flags = __ballot(v >> 31);
        while (flags) {
            int j = __ffsll(flags) - 1;
            flags &= flags - 1;
            long long p = base + j;
            const float* __restrict__ xp = x + p * D;
            double bt = -1e300;
            int bk = 0;
            for (int k = lane; k < K; k += 64) {   // ascending k per lane; strict > = first-occurrence
                double t = 0.0, s = 0.0;
                #pragma unroll 8
                for (int d = 0; d < D; ++d) {
                    double wd = (double)w[(size_t)d * K + k];
                    t = fma((double)xp[d], wd, t);
                    s = fma(wd, wd, s);
                }
                t -= 0.5 * s;
                if (t > bt) { bt = t; bk = k; }
            }
            #pragma unroll
            for (int off = 32; off > 0; off >>= 1) {
                double ot = __shfl_down(bt, off);
                int    ok = __shfl_down(bk, off);
                if (ot > bt || (ot == bt && ok < bk)) { bt = ot; bk = ok; }
            }
            int fk = __shfl(bk, 0);
            if (lane == 0) idx_io[p] = (unsigned)fk;     // clear flag
        }
    }
}

// ---------------- K4: fused quantized-gather + EMA scatter (wave per point) ----------------
__global__ void k_scatgat(const float* __restrict__ x, const float* __restrict__ wT,
                          const unsigned int* __restrict__ idx, float* __restrict__ quant,
                          float* __restrict__ cs, float* __restrict__ cn, int N, int K, int NP)
{
    const int gtid = blockIdx.x * blockDim.x + threadIdx.x;
    const int lane = threadIdx.x & 63;
    const long long wave = gtid >> 6;
    const long long nwaves = (long long)(gridDim.x * blockDim.x) >> 6;
    const int part = blockIdx.x % NP;
    float* csp = cs + (size_t)part * K * D;
    float* cnp = cn + (size_t)part * K;
    for (long long p = wave; p < N; p += nwaves) {
        unsigned k = idx[p] & 0x7fffffffu;
        float v = x[p * D + lane];
        quant[p * D + lane] = wT[(size_t)k * D + lane];       // coalesced 256B gather (L2-hot)
        unsafeAtomicAdd(&csp[(size_t)k * D + lane], v);       // coalesced 256B atomic burst
        if (lane == 0) unsafeAtomicAdd(&cnp[k], 1.0f);
    }
}

// ---------------- K5: reduce NP partials + EMA combine -> new_w [D][K] ----------------
__global__ void k_combine(const float* __restrict__ c_sum, const float* __restrict__ c_n,
                          const float* __restrict__ cs, const float* __restrict__ cn,
                          float* __restrict__ outw, int K, int NP)
{
    int i = blockIdx.x * blockDim.x + threadIdx.x;   // i = d*K + k
    if (i >= D * K) return;
    int k = i % K;
    int d = i / K;
    float s = 0.f, nk = 0.f;
    for (int p = 0; p < NP; ++p) {
        s  += cs[(size_t)p * K * D + (size_t)k * D + d];
        nk += cn[(size_t)p * K + k];
    }
    const float g  = 0.99f;
    const float og = (float)(1.0 - 0.99);
    float ns = c_sum[i] * g + s * og;
    float nn = c_n[k] * g + nk * og;
    outw[i] = ns / nn;
}

extern "C" void kernel_launch(void* const* d_in, const int* in_sizes, int n_in,
                              void* d_out, int out_size, void* d_ws, size_t ws_size,
                              hipStream_t stream)
{
    const float* x     = (const float*)d_in[0];
    const float* w     = (const float*)d_in[1];
    const float* c_sum = (const float*)d_in[2];
    const float* c_n   = (const float*)d_in[3];
    const int N = in_sizes[0] / D;
    const int K = in_sizes[3];

    float* quant = (float*)d_out;                      // N*D
    float* outw  = (float*)d_out + (size_t)N * D;      // D*K

    // workspace layout (all 16B-aligned): cs | cn | wn | wT | idx | wpack_hi | wpack_lo
    size_t fixed = (size_t)K * 4 + (size_t)K * D * 4 + (size_t)N * 4 + (size_t)K * D * 2 * 2;
    int NP = NPMAX;
    while (NP > 1 && fixed + (size_t)NP * K * (D + 1) * 4 > ws_size) NP >>= 1;

    char* ws = (char*)d_ws;
    float* cs = (float*)ws;                                            // NP*K*D
    float* cn = cs + (size_t)NP * K * D;                               // NP*K
    float* wn = cn + (size_t)NP * K;                                   // K
    float* wT = wn + K;                                                // K*D
    unsigned* idx = (unsigned*)(wT + (size_t)K * D);                   // N
    unsigned short* wpack_hi = (unsigned short*)(idx + N);             // K*D
    unsigned short* wpack_lo = wpack_hi + (size_t)K * D;               // K*D

    hipMemsetAsync(cs, 0, (size_t)NP * K * (D + 1) * sizeof(float), stream);
    k_prep_w<<<(D * K + 255) / 256, 256, 0, stream>>>(w, wpack_hi, wpack_lo, wT, K);
    k_wn<<<(K + 255) / 256, 256, 0, stream>>>(w, wn, K);

    int grid_assign = (N + 127) / 128;                                 // 2048 blocks
    k_assign<<<grid_assign, 256, 0, stream>>>(x, wpack_hi, wpack_lo, wn, idx, N, K);

    // 4096 waves = one 64-point chunk per wave: flagged points ~0.2/wave
    k_refine<<<1024, 256, 0, stream>>>(x, w, idx, N, K);
    k_scatgat<<<1024, 256, 0, stream>>>(x, wT, idx, quant, cs, cn, N, K, NP);
    k_combine<<<(D * K + 255) / 256, 256, 0, stream>>>(c_sum, c_n, cs, cn, outw, K, NP);
}